// Round 1
// baseline (103.607 us; speedup 1.0000x reference)
//
#include <hip/hip_runtime.h>
#include <math.h>

#define N 16384
#define LIMIT 8192

// key = (float_bits(score) << 14) | index  -- 44-bit unique sort key.
// score = sigmoid(y) in (0,1], positive => float bits monotone in value,
// bits <= 0x3F800000 < 2^30, index < 2^14. Lexicographic (score, index)
// matches jnp.argsort(stable) tie-breaking exactly.
__device__ __forceinline__ unsigned long long make_key(float s, int i) {
    return ((unsigned long long)__float_as_uint(s) << 14) | (unsigned int)i;
}

__global__ void score_kernel(const float* __restrict__ x,
                             const float* __restrict__ w,
                             float* __restrict__ score) {
    int i = blockIdx.x * blockDim.x + threadIdx.x;
    if (i >= N) return;
    // y[i] = sum_{t=0..6} x[i+t-3] * w[t]; zero-padded borders.
    // Non-contracted mul+add in sequential order to mirror numpy's f32
    // accumulation (FMA would change last-ulp rounding => boundary risk).
    float acc = 0.f;
#pragma unroll
    for (int t = 0; t < 7; ++t) {
        int j = i + t - 3;
        float xv = (j >= 0 && j < N) ? x[j] : 0.f;
        acc = __fadd_rn(acc, __fmul_rn(xv, w[t]));
    }
    float s = 1.f / (1.f + expf(-acc));
    score[i] = s;
}

// Single-block MSB-first radix select: finds the key with rank LIMIT-1
// (0-indexed) among all N keys. 4 passes x 11 bits over the 44-bit key.
__global__ __launch_bounds__(1024) void select_kernel(const float* __restrict__ score,
                                                      unsigned long long* __restrict__ thresh) {
    __shared__ unsigned int hist[2048];
    __shared__ unsigned int partial[256];
    __shared__ unsigned long long prefix_sh;
    __shared__ int r_sh;
    const int tid = threadIdx.x;
    if (tid == 0) { prefix_sh = 0ULL; r_sh = LIMIT - 1; }
    __syncthreads();

    for (int pass = 0; pass < 4; ++pass) {
        const int shift = 33 - 11 * pass;   // chunks [43:33],[32:22],[21:11],[10:0]
        for (int b = tid; b < 2048; b += 1024) hist[b] = 0;
        __syncthreads();
        const unsigned long long prefix = prefix_sh;
        for (int idx = tid; idx < N; idx += 1024) {
            unsigned long long key = make_key(score[idx], idx);
            if ((key >> (shift + 11)) == prefix)
                atomicAdd(&hist[(unsigned int)(key >> shift) & 2047u], 1u);
        }
        __syncthreads();
        if (tid < 256) {
            unsigned int s = 0;
#pragma unroll
            for (int k = 0; k < 8; ++k) s += hist[tid * 8 + k];
            partial[tid] = s;
        }
        __syncthreads();
        if (tid == 0) {
            const unsigned int r = (unsigned int)r_sh;
            unsigned int cum = 0;
            int g = 0;
            for (; g < 256; ++g) {
                unsigned int p = partial[g];
                if (cum + p > r) break;
                cum += p;
            }
            int b = g * 8;
            for (;; ++b) {
                unsigned int c = hist[b];
                if (cum + c > r) break;
                cum += c;
            }
            r_sh = (int)(r - cum);
            prefix_sh = (prefix << 11) | (unsigned long long)b;
        }
        __syncthreads();
    }
    if (tid == 0) thresh[0] = prefix_sh;
}

__global__ void output_kernel(const float* __restrict__ x,
                              const float* __restrict__ score,
                              const unsigned long long* __restrict__ thresh,
                              float* __restrict__ new_x) {
    int i = blockIdx.x * blockDim.x + threadIdx.x;
    if (i >= N) return;
    unsigned long long T = thresh[0];          // uniform scalar load
    float s = score[i];
    unsigned long long key = make_key(s, i);
    new_x[i] = (key <= T) ? x[i] * (s + 1.0f) : 0.f;
}

extern "C" void kernel_launch(void* const* d_in, const int* in_sizes, int n_in,
                              void* d_out, int out_size, void* d_ws, size_t ws_size,
                              hipStream_t stream) {
    const float* x = (const float*)d_in[0];
    const float* w = (const float*)d_in[1];
    float* out = (float*)d_out;                 // [0:N) new_x, [N:2N) attention_score
    float* score = out + N;
    unsigned long long* thresh = (unsigned long long*)d_ws;

    score_kernel<<<N / 256, 256, 0, stream>>>(x, w, score);
    select_kernel<<<1, 1024, 0, stream>>>(score, thresh);
    output_kernel<<<N / 256, 256, 0, stream>>>(x, score, thresh, out);
}

// Round 2
// 70.513 us; speedup vs baseline: 1.4693x; 1.4693x over previous
//
#include <hip/hip_runtime.h>
#include <math.h>

#define N 16384
#define LIMIT 8192
#define NT 1024
#define EPT 16   // elements per thread (contiguous chunk)

// key = (float_bits(score) << 14) | index  -- 44-bit unique sort key.
// score = sigmoid(y) in (0,1) => positive float, bits < 2^30, monotone in value;
// index < 2^14. Lexicographic (score, index) == jnp stable argsort order.
// Rank-(LIMIT-1) key T found by 4x11-bit MSB radix select; keep iff key <= T.
__global__ __launch_bounds__(1024) void fused_kernel(const float* __restrict__ x,
                                                     const float* __restrict__ w,
                                                     float* __restrict__ out) {
    __shared__ unsigned int hist[2048];
    __shared__ unsigned int partial[256];
    __shared__ unsigned long long prefix_sh;
    __shared__ unsigned int r_sh;

    const int tid = threadIdx.x;
    const int base = tid * EPT;

    // ---- weights (wave-uniform scalar loads) ----
    float wv[7];
#pragma unroll
    for (int t = 0; t < 7; ++t) wv[t] = w[t];

    // ---- x window [base-3, base+EPT+3) in registers ----
    float win[EPT + 6];
    const float4* xv = (const float4*)(x + base);
#pragma unroll
    for (int q = 0; q < 4; ++q) {
        float4 v = xv[q];
        win[3 + 4*q + 0] = v.x; win[3 + 4*q + 1] = v.y;
        win[3 + 4*q + 2] = v.z; win[3 + 4*q + 3] = v.w;
    }
#pragma unroll
    for (int t = 0; t < 3; ++t) {
        int jl = base - 3 + t;
        win[t] = (jl >= 0) ? x[jl] : 0.f;
        int jr = base + EPT + t;
        win[EPT + 3 + t] = (jr < N) ? x[jr] : 0.f;
    }

    // ---- conv + sigmoid (bit-exact: sequential non-contracted mul/add, expf) ----
    float s[EPT];
#pragma unroll
    for (int k = 0; k < EPT; ++k) {
        float acc = 0.f;
#pragma unroll
        for (int t = 0; t < 7; ++t)
            acc = __fadd_rn(acc, __fmul_rn(win[k + t], wv[t]));
        s[k] = 1.f / (1.f + expf(-acc));
    }

    // ---- store attention_score (output 1) ----
    float4* so = (float4*)(out + N + base);
#pragma unroll
    for (int q = 0; q < 4; ++q)
        so[q] = make_float4(s[4*q], s[4*q+1], s[4*q+2], s[4*q+3]);

    if (tid == 0) { prefix_sh = 0ULL; r_sh = LIMIT - 1; }

    // ---- radix select: 4 passes x 11 bits over the 44-bit key ----
    for (int pass = 0; pass < 4; ++pass) {
        const int shift = 33 - 11 * pass;   // chunks [43:33],[32:22],[21:11],[10:0]
        hist[tid] = 0u; hist[tid + 1024] = 0u;
        __syncthreads();                    // covers init on pass 0, stage-B of prior pass
        const unsigned long long prefix = prefix_sh;
        const unsigned int r = r_sh;
#pragma unroll
        for (int k = 0; k < EPT; ++k) {
            unsigned long long key = ((unsigned long long)__float_as_uint(s[k]) << 14)
                                     | (unsigned int)(base + k);
            if ((key >> (shift + 11)) == prefix)  // pass 0: key>>44==0==prefix, all match
                atomicAdd(&hist[(unsigned int)(key >> shift) & 2047u], 1u);
        }
        __syncthreads();
        if (tid < 256) {
            unsigned int p = 0;
#pragma unroll
            for (int k = 0; k < 8; ++k) p += hist[tid * 8 + k];
            partial[tid] = p;
        }
        __syncthreads();
        if (tid < 64) {   // wave 0 only: wave-synchronous, no barriers needed inside
            unsigned int p0 = partial[4*tid+0], p1 = partial[4*tid+1],
                         p2 = partial[4*tid+2], p3 = partial[4*tid+3];
            const unsigned int g = p0 + p1 + p2 + p3;
            unsigned int incl = g;
#pragma unroll
            for (int d = 1; d < 64; d <<= 1) {
                unsigned int up = __shfl_up(incl, d, 64);
                if (tid >= d) incl += up;
            }
            unsigned long long ball = __ballot(incl > r);  // nonzero by rank invariant
            int L = __ffsll((unsigned long long)ball) - 1;
            if (tid == L) {
                unsigned int cum = incl - g;     // exclusive prefix of this lane's 4 groups
                unsigned int pp[4] = {p0, p1, p2, p3};
                int grp = -1;
#pragma unroll
                for (int k2 = 0; k2 < 4; ++k2) {
                    if (grp < 0) {
                        if (cum + pp[k2] > r) grp = 4*L + k2;
                        else cum += pp[k2];
                    }
                }
                unsigned int c[8];
#pragma unroll
                for (int k2 = 0; k2 < 8; ++k2) c[k2] = hist[grp*8 + k2];  // batched loads
                int b = -1;
#pragma unroll
                for (int k2 = 0; k2 < 8; ++k2) {
                    if (b < 0) {
                        if (cum + c[k2] > r) b = grp*8 + k2;
                        else cum += c[k2];
                    }
                }
                r_sh = r - cum;
                prefix_sh = (prefix << 11) | (unsigned long long)b;
            }
        }
        __syncthreads();
    }
    const unsigned long long T = prefix_sh;   // full key of the rank-(LIMIT-1) element

    // ---- output 0: new_x ----
    float4* no = (float4*)(out + base);
#pragma unroll
    for (int q = 0; q < 4; ++q) {
        float4 v;
        float* vp = &v.x;
#pragma unroll
        for (int e = 0; e < 4; ++e) {
            int k = 4*q + e;
            unsigned long long key = ((unsigned long long)__float_as_uint(s[k]) << 14)
                                     | (unsigned int)(base + k);
            vp[e] = (key <= T) ? __fmul_rn(win[3 + k], __fadd_rn(s[k], 1.0f)) : 0.f;
        }
        no[q] = v;
    }
}

extern "C" void kernel_launch(void* const* d_in, const int* in_sizes, int n_in,
                              void* d_out, int out_size, void* d_ws, size_t ws_size,
                              hipStream_t stream) {
    const float* x = (const float*)d_in[0];
    const float* w = (const float*)d_in[1];
    float* out = (float*)d_out;   // [0:N) new_x, [N:2N) attention_score
    fused_kernel<<<1, NT, 0, stream>>>(x, w, out);
}

// Round 3
// 69.518 us; speedup vs baseline: 1.4904x; 1.0143x over previous
//
#include <hip/hip_runtime.h>
#include <math.h>

#define N 16384
#define LIMIT 8192
#define NT 1024
#define EPT 16   // elements per thread (contiguous chunk)

// key = (float_bits(score) << 14) | index  -- 44-bit unique sort key.
// score = sigmoid(y) in (0,1] => positive float, bits <= 0x3F800000 < 2^30,
// monotone in value; index < 2^14. Lexicographic (score, index) matches jnp
// stable argsort. Rank-(LIMIT-1) key T via MSB radix select, keep iff key<=T.
// Pass widths 10+12+11+11 = 44. Pass 0 uses an 8-way-spread histogram to kill
// same-address LDS atomic serialization (scores cluster into ~16 hot buckets).
__global__ __launch_bounds__(1024) void fused_kernel(const float* __restrict__ x,
                                                     const float* __restrict__ w,
                                                     float* __restrict__ out) {
    __shared__ unsigned int hist0[1024 * 8];  // pass-0 spread histogram (32KB)
    __shared__ unsigned int tot[4096];        // per-pass bin totals (16KB)
    __shared__ unsigned int partial[256];
    __shared__ unsigned long long prefix_sh;
    __shared__ unsigned int r_sh;

    const int tid = threadIdx.x;
    const int base = tid * EPT;

    // ---- weights (uniform scalar loads) ----
    float wv[7];
#pragma unroll
    for (int t = 0; t < 7; ++t) wv[t] = w[t];

    // ---- x window [base-3, base+EPT+3) in registers ----
    float win[EPT + 6];
    const float4* xv = (const float4*)(x + base);
#pragma unroll
    for (int q = 0; q < 4; ++q) {
        float4 v = xv[q];
        win[3 + 4*q + 0] = v.x; win[3 + 4*q + 1] = v.y;
        win[3 + 4*q + 2] = v.z; win[3 + 4*q + 3] = v.w;
    }
#pragma unroll
    for (int t = 0; t < 3; ++t) {
        int jl = base - 3 + t;
        win[t] = (jl >= 0) ? x[jl] : 0.f;
        int jr = base + EPT + t;
        win[EPT + 3 + t] = (jr < N) ? x[jr] : 0.f;
    }

    // ---- conv + sigmoid (bit-exact: sequential non-contracted mul/add, expf) ----
    float s[EPT];
#pragma unroll
    for (int k = 0; k < EPT; ++k) {
        float acc = 0.f;
#pragma unroll
        for (int t = 0; t < 7; ++t)
            acc = __fadd_rn(acc, __fmul_rn(win[k + t], wv[t]));
        s[k] = 1.f / (1.f + expf(-acc));
    }

    // ---- store attention_score (output 1) ----
    float4* so = (float4*)(out + N + base);
#pragma unroll
    for (int q = 0; q < 4; ++q)
        so[q] = make_float4(s[4*q], s[4*q+1], s[4*q+2], s[4*q+3]);

    // ---- zero pass-0 arrays ----
#pragma unroll
    for (int q = 0; q < 8; ++q) hist0[tid + q * 1024] = 0u;
#pragma unroll
    for (int q = 0; q < 4; ++q) tot[tid + q * 1024] = 0u;
    if (tid == 0) { prefix_sh = 0ULL; r_sh = LIMIT - 1; }
    __syncthreads();

    // scan/select over tot[0..256*W): group sums -> wave-0 shfl scan -> walk.
    auto scan_select = [&](int W, int width) {
        const unsigned int r = r_sh;
        if (tid < 256) {
            unsigned int p = 0;
            for (int q = 0; q < W / 4; ++q) {
                uint4 v = ((const uint4*)tot)[tid * (W / 4) + q];
                p += v.x + v.y + v.z + v.w;
            }
            partial[tid] = p;
        }
        __syncthreads();
        if (tid < 64) {   // wave 0: wave-synchronous
            unsigned int p0 = partial[4*tid+0], p1 = partial[4*tid+1],
                         p2 = partial[4*tid+2], p3 = partial[4*tid+3];
            const unsigned int g4 = p0 + p1 + p2 + p3;
            unsigned int incl = g4;
#pragma unroll
            for (int d = 1; d < 64; d <<= 1) {
                unsigned int up = __shfl_up(incl, d, 64);
                if (tid >= d) incl += up;
            }
            unsigned long long ball = __ballot(incl > r);  // nonzero by rank invariant
            int L = __ffsll((unsigned long long)ball) - 1;
            if (tid == L) {
                unsigned int cum = incl - g4;
                unsigned int pp[4] = {p0, p1, p2, p3};
                int grp = -1;
#pragma unroll
                for (int k2 = 0; k2 < 4; ++k2) {
                    if (grp < 0) {
                        if (cum + pp[k2] > r) grp = 4*L + k2;
                        else cum += pp[k2];
                    }
                }
                unsigned int c[16];
                for (int q = 0; q < W / 4; ++q) {   // batched uint4 LDS loads
                    uint4 v = ((const uint4*)tot)[grp * (W / 4) + q];
                    c[4*q+0] = v.x; c[4*q+1] = v.y; c[4*q+2] = v.z; c[4*q+3] = v.w;
                }
                int b = -1;
#pragma unroll
                for (int k2 = 0; k2 < 16; ++k2) {
                    if (k2 < W && b < 0) {
                        if (cum + c[k2] > r) b = grp * W + k2;
                        else cum += c[k2];
                    }
                }
                r_sh = r - cum;
                prefix_sh = (prefix_sh << width) | (unsigned long long)b;
            }
        }
        __syncthreads();
    };

    // ---- pass 0: key bits [43:34] (10 bits), 8-way spread ----
    const int slot = tid & 7;
#pragma unroll
    for (int k = 0; k < EPT; ++k) {
        unsigned long long key = ((unsigned long long)__float_as_uint(s[k]) << 14)
                                 | (unsigned int)(base + k);
        unsigned int bin = (unsigned int)(key >> 34);   // < 1024
        atomicAdd(&hist0[bin * 8 + slot], 1u);
    }
    __syncthreads();
    {   // collapse spread: tot[bin] = sum of 8 copies
        uint4 a = ((const uint4*)hist0)[tid * 2];
        uint4 b = ((const uint4*)hist0)[tid * 2 + 1];
        tot[tid] = a.x + a.y + a.z + a.w + b.x + b.y + b.z + b.w;
    }
    __syncthreads();
    scan_select(4, 10);

    // ---- passes 1..3: widths 12,11,11; shifts 22,11,0 ----
    const int widths[3] = {12, 11, 11};
    const int shifts[3] = {22, 11, 0};
    const int nbins[3]  = {4096, 2048, 2048};
#pragma unroll
    for (int p = 0; p < 3; ++p) {
        const int width = widths[p], shift = shifts[p], B = nbins[p];
        for (int b = tid; b < B; b += 1024) tot[b] = 0u;
        __syncthreads();
        const unsigned long long prefix = prefix_sh;
#pragma unroll
        for (int k = 0; k < EPT; ++k) {
            unsigned long long key = ((unsigned long long)__float_as_uint(s[k]) << 14)
                                     | (unsigned int)(base + k);
            if ((key >> (shift + width)) == prefix)
                atomicAdd(&tot[(unsigned int)(key >> shift) & (unsigned int)(B - 1)], 1u);
        }
        __syncthreads();
        scan_select(B / 256, width);
    }
    const unsigned long long T = prefix_sh;   // full 44-bit rank-(LIMIT-1) key

    // ---- output 0: new_x ----
    float4* no = (float4*)(out + base);
#pragma unroll
    for (int q = 0; q < 4; ++q) {
        float4 v;
        float* vp = &v.x;
#pragma unroll
        for (int e = 0; e < 4; ++e) {
            int k = 4*q + e;
            unsigned long long key = ((unsigned long long)__float_as_uint(s[k]) << 14)
                                     | (unsigned int)(base + k);
            vp[e] = (key <= T) ? __fmul_rn(win[3 + k], __fadd_rn(s[k], 1.0f)) : 0.f;
        }
        no[q] = v;
    }
}

extern "C" void kernel_launch(void* const* d_in, const int* in_sizes, int n_in,
                              void* d_out, int out_size, void* d_ws, size_t ws_size,
                              hipStream_t stream) {
    const float* x = (const float*)d_in[0];
    const float* w = (const float*)d_in[1];
    float* out = (float*)d_out;   // [0:N) new_x, [N:2N) attention_score
    fused_kernel<<<1, NT, 0, stream>>>(x, w, out);
}